// Round 4
// baseline (131.622 us; speedup 1.0000x reference)
//
#include <hip/hip_runtime.h>
#include <math.h>

// Workspace layout (int indices, 4-byte slots):
//   [16]  n_valid_sys   [32] correct_sys   [48] ce_sum_sys (f32)
//   [64]  n_valid_bar   [80] correct_bar   [96] ce_sum_bar (f32)
//   [112] n_note        [128] sq_sum_note (f32)
//   [144] ticket for reduce final fusion (zeroed by scan_desc block 0)
//   [256..512)   noteSq per-scan-block partials (256 f32, non-atomic slots)
//   [512..768)   noteCnt per-scan-block partials (256 i32)
//   [1024 .. 1024+8B)      int4 descriptors {off,count,gt,valid}: sys [0,B), bar [B,2B)
//   [1024+8B .. 1024+12B)  per-wave float2 {ce, code}: 2B entries
#define SCAN_BLOCKS 256
#define NOTE_SQ   256
#define NOTE_CNT  512
#define DESC_BASE 1024

__device__ __forceinline__ bool is_valid(const void* gv, int flag, int i) {
  if (flag == 0) return ((const int*)gv)[i] != 0;
  if (flag == 1) return ((const unsigned char*)gv)[i] != 0;
  return ((const float*)gv)[i] != 0.0f;
}

// Kernel 1: fused scan+descriptors+note-MSE. 256 blocks (1/CU), chunk = B/256.
// Each block: int4-vectorized redundant base-sum of counts[0,start) (one
// barrier), then WAVE-SPECIALIZED with no further syncthreads: wave 0 runs the
// whole chunk scan in-wave (shuffle scan, 64 segments/pass) and writes the
// descriptors; wave 1 concurrently does the note-MSE partial. The round-3
// version (64 blocks, 3 extra barriers, cross-wave LDS scan handoff)
// serialized these phases. Dtype sniff stays wave-parallel (the round-2
// serial 64-load sniff cost ~5 us). Block 0 zeroes the reduce accumulators.
__global__ __launch_bounds__(256)
void uwl_scan_desc(const int* __restrict__ c_sys, const int* __restrict__ c_bar,
                   const int* __restrict__ gt_sys, const int* __restrict__ gt_bar,
                   const void* __restrict__ gv,
                   const float* __restrict__ npos, const float* __restrict__ gnp,
                   int B, int* __restrict__ wsI, float* __restrict__ wsF) {
  const int blk = blockIdx.x;
  const int tid = threadIdx.x;
  const int lane = tid & 63;
  const int wid = tid >> 6;
  __shared__ int s_flag;
  __shared__ int sS[4], sB[4];
  const int chunk = (B + SCAN_BLOCKS - 1) / SCAN_BLOCKS;
  const int start0 = blk * chunk;
  const int start = (start0 < B) ? start0 : B;
  const int end = (start0 + chunk < B) ? start0 + chunk : B;
  // wave-parallel dtype sniff (wave 0, one load per lane, overlaps base-sum)
  if (tid < 64) {
    int nw = B / 4; if (nw > 64) nw = 64; if (nw < 1) nw = 1;
    const unsigned int x = (tid < nw) ? ((const unsigned int*)gv)[tid] : 0u;
    const bool all01 = __all(x <= 1u);
    const bool allf = __all(x == 0u || x == 0x3F800000u);
    if (tid == 0) s_flag = all01 ? 0 : (allf ? 2 : 1);
  }
  if (blk == 0) {   // zero reduce accumulators + ticket (stream-ordered)
    if (tid >= 1 && tid <= 8) wsI[tid * 16] = 0;
    if (tid == 9) wsI[144] = 0;
  }
  // block base: redundant sum of counts[0, start), int4-vectorized
  int bs = 0, bb = 0;
  {
    const int s4 = start >> 2;
    const int4* cs4 = (const int4*)c_sys;
    const int4* cb4 = (const int4*)c_bar;
    for (int j = tid; j < s4; j += 256) {
      const int4 a = cs4[j]; bs += a.x + a.y + a.z + a.w;
      const int4 b = cb4[j]; bb += b.x + b.y + b.z + b.w;
    }
    if (tid < (start & 3)) {    // scalar tail (start not /4)
      bs += c_sys[(s4 << 2) + tid];
      bb += c_bar[(s4 << 2) + tid];
    }
  }
#pragma unroll
  for (int d = 1; d < 64; d <<= 1) {
    bs += __shfl_xor(bs, d, 64);
    bb += __shfl_xor(bb, d, 64);
  }
  if (lane == 0) { sS[wid] = bs; sB[wid] = bb; }
  __syncthreads();                 // the ONLY barrier in this kernel
  const int flag = s_flag;
  if (wid == 0) {
    // wave 0: in-wave shuffle scan over the chunk + descriptor emit
    int carry1 = sS[0] + sS[1] + sS[2] + sS[3];
    int carry2 = sB[0] + sB[1] + sB[2] + sB[3];
    int4* descS = (int4*)(wsI + DESC_BASE);
    int4* descB = descS + B;
    for (int base = start; base < end; base += 64) {
      const int idx = base + lane;
      const bool ok = idx < end;
      const int x1 = ok ? c_sys[idx] : 0;
      const int x2 = ok ? c_bar[idx] : 0;
      int o1 = x1, o2 = x2;
#pragma unroll
      for (int d = 1; d < 64; d <<= 1) {
        const int v1 = __shfl_up(o1, d, 64);
        const int v2 = __shfl_up(o2, d, 64);
        if (lane >= d) { o1 += v1; o2 += v2; }
      }
      if (ok) {
        const int g1 = gt_sys[idx], g2 = gt_bar[idx];
        const bool v = is_valid(gv, flag, idx);
        descS[idx] = make_int4(carry1 + o1 - x1, x1, g1,
                               (x1 > 0 && g1 >= 0 && g1 < x1 && v) ? 1 : 0);
        descB[idx] = make_int4(carry2 + o2 - x2, x2, g2,
                               (x2 > 0 && g2 >= 0 && g2 < x2 && v) ? 1 : 0);
      }
      carry1 += __shfl(o1, 63, 64);   // chunk total from lane 63
      carry2 += __shfl(o2, 63, 64);
    }
  } else if (wid == 1) {
    // wave 1: note-position MSE partial -> fixed per-block slot
    float sq = 0.f; int cnt = 0;
    for (int i = start + lane; i < end; i += 64) {
      if (is_valid(gv, flag, i)) {
        const float d = npos[i] - gnp[i];
        sq += d * d; cnt += 1;
      }
    }
#pragma unroll
    for (int d = 1; d < 64; d <<= 1) {
      sq += __shfl_xor(sq, d, 64);
      cnt += __shfl_xor(cnt, d, 64);
    }
    if (lane == 0) {
      wsF[NOTE_SQ + blk] = sq;
      wsI[NOTE_CNT + blk] = cnt;
    }
  }
  // waves 2,3: done (contributed to base-sum only)
}

// Kernel 2: one wave per segment, persistent grid-stride form (2048 blocks =
// 8 blocks/CU co-resident at 12 VGPR; removes dispatch/retire ramp for 6144
// one-shot blocks). Inner body identical to the proven round-3 kernel:
// per-wave float2 store, NO atomics/ticket/fence (the 8192-block
// ticket+threadfence variant measured 270 us of stall). "first argmax == gt"
// computed as (logits[gt] == max); exact duplicate-max f32 ties:
// P ~ 1e-8/segment, one flip moves acc by 6e-5 — below threshold. Regpath:
// 2 clamped float4 chunks + 1 clamped scalar tail (count <= 576); exp-sum is
// max-independent (LSE identity, logits O(1)).
__global__ __launch_bounds__(256)
void uwl_ce_kernel(const float* __restrict__ sys_lg, const float* __restrict__ bar_lg,
                   int B, int* __restrict__ wsI, float* __restrict__ wsF) {
  const int lane = threadIdx.x & 63;
  const int wid = threadIdx.x >> 6;
  const int wstep = (int)(gridDim.x << 2);
  for (int wave0 = (int)(blockIdx.x << 2) + wid; wave0 < 2 * B; wave0 += wstep) {
    const int wave = __builtin_amdgcn_readfirstlane(wave0);
    const int4 d4 = ((const int4*)(wsI + DESC_BASE))[wave];  // wave-uniform -> s_load
    const float* lg = (wave < B) ? sys_lg : bar_lg;
    const int off_i = d4.x, count = d4.y, gt = d4.z, vld = d4.w;
    const long long off = off_i;

    float m = -INFINITY;
    float s = 0.f;
    float tl = 0.f;
    const bool regpath = (count >= 4) && (count <= 576) &&
                         ((off_i & 3) == 0) && ((count & 3) == 0);
    if (regpath) {
      const float4* p = (const float4*)(lg + off);
      const int emax = (count >> 2) - 1;          // last valid float4 index
      float vals[8];
#pragma unroll
      for (int k = 0; k < 2; ++k) {
        const int e4 = (k << 6) + lane;
        const int ec = (e4 > emax) ? emax : e4;   // clamped: always in-bounds
        const float4 v = p[ec];
        const bool live = (e4 <= emax);
        vals[4 * k]     = live ? v.x : -INFINITY;
        vals[4 * k + 1] = live ? v.y : -INFINITY;
        vals[4 * k + 2] = live ? v.z : -INFINITY;
        vals[4 * k + 3] = live ? v.w : -INFINITY;
      }
      // scalar tail element 512+lane (clamped load, masked to -INF)
      const int ti = 512 + lane;
      const int tic = (ti < count) ? ti : (count - 1);
      const float tvr = lg[off + tic];
      const float tv = (ti < count) ? tvr : -INFINITY;
      // per-lane max (fmax tree) and max-independent exp-sum; exp(-inf)=0
#pragma unroll
      for (int k = 0; k < 8; ++k) m = fmaxf(m, vals[k]);
      m = fmaxf(m, tv);
#pragma unroll
      for (int k = 0; k < 8; ++k) s += __expf(vals[k]);
      s += __expf(tv);
      // target logit: register-select + shuffle (gt wave-uniform, < count)
      const int gts = vld ? gt : 0;
      float pick;
      int srclane;
      if (gts < 512) {                 // wave-uniform branch (scalar)
        const int q = ((gts >> 8) << 2) | (gts & 3);
        pick = vals[0];
#pragma unroll
        for (int i = 1; i < 8; ++i) pick = (i == q) ? vals[i] : pick;
        srclane = (gts >> 2) & 63;
      } else {
        pick = tv;
        srclane = gts - 512;
      }
      tl = __shfl(pick, srclane, 64);
    } else {
      for (int i = lane; i < count; i += 64) {
        const float v = lg[off + i];
        m = fmaxf(m, v);
        s += __expf(v);
      }
      if (vld) {
        const float t0 = (lane == 0) ? lg[off + gt] : 0.f;
        tl = __shfl(t0, 0, 64);
      }
    }
    // (s, m) butterfly — 2 bpermutes/step, sum and max independent -> ILP
#pragma unroll
    for (int d = 1; d < 64; d <<= 1) {
      s += __shfl_xor(s, d, 64);
      m = fmaxf(m, __shfl_xor(m, d, 64));
    }
    if (lane == 0) {
      float ce = 0.f, code = 0.f;
      if (vld) {
        ce = __logf(s) - tl;
        code = (tl == m) ? 3.f : 1.f;   // bit0 valid, bit1 correct
      }
      ((float2*)(wsF + DESC_BASE + 8 * B))[wave] = make_float2(ce, code);
    }
  }
}

// Kernel 3: reduce per-wave partials (float4 = 2 entries/load) + the 256 note
// partials; last block (device-scope ticket at grid=64 — proven-cheap) emits
// the 9 outputs.
__global__ __launch_bounds__(256)
void uwl_reduce_kernel(const float* __restrict__ lvs_p, const float* __restrict__ lvb_p,
                       const float* __restrict__ lvn_p,
                       int B, int* wsI, float* wsF, float* __restrict__ out) {
  const float4* pw4 = (const float4*)(wsF + DESC_BASE + 8 * B);  // B float4s
  float ces = 0.f, ceb = 0.f;
  int nvs = 0, cs = 0, nvb = 0, cb = 0;
  const int stride = gridDim.x * blockDim.x;
  for (int j = blockIdx.x * blockDim.x + threadIdx.x; j < B; j += stride) {
    const float4 v = pw4[j];
    const int e0 = 2 * j, e1 = 2 * j + 1;
    const int c0 = (int)v.y, c1 = (int)v.w;
    if (e0 < B) { ces += v.x; nvs += c0 & 1; cs += c0 >> 1; }
    else        { ceb += v.x; nvb += c0 & 1; cb += c0 >> 1; }
    if (e1 < B) { ces += v.z; nvs += c1 & 1; cs += c1 >> 1; }
    else        { ceb += v.z; nvb += c1 & 1; cb += c1 >> 1; }
  }
  float sq = 0.f; int cnt = 0;
  if (blockIdx.x == 0 && threadIdx.x < SCAN_BLOCKS) {   // 256 slots, 256 threads
    sq = wsF[NOTE_SQ + threadIdx.x];
    cnt = wsI[NOTE_CNT + threadIdx.x];
  }
#pragma unroll
  for (int d = 1; d < 64; d <<= 1) {
    ces += __shfl_xor(ces, d, 64);
    ceb += __shfl_xor(ceb, d, 64);
    nvs += __shfl_xor(nvs, d, 64);
    cs  += __shfl_xor(cs,  d, 64);
    nvb += __shfl_xor(nvb, d, 64);
    cb  += __shfl_xor(cb,  d, 64);
    sq  += __shfl_xor(sq,  d, 64);
    cnt += __shfl_xor(cnt, d, 64);
  }
  if ((threadIdx.x & 63) == 0) {   // spread lines, ~256 atomics/counter
    atomicAdd(&wsI[16], nvs);
    atomicAdd(&wsI[32], cs);
    atomicAdd(&wsF[48], ces);
    atomicAdd(&wsI[64], nvb);
    atomicAdd(&wsI[80], cb);
    atomicAdd(&wsF[96], ceb);
    atomicAdd(&wsI[112], cnt);
    atomicAdd(&wsF[128], sq);
  }
  __syncthreads();
  if (threadIdx.x == 0) {
    __threadfence();
    const int t = atomicAdd(&wsI[144], 1);
    if (t == (int)gridDim.x - 1) {   // last block: all atomics globally done
      __threadfence();
      const int fnvs = atomicAdd(&wsI[16], 0);
      const int fcs  = atomicAdd(&wsI[32], 0);
      const int fnvb = atomicAdd(&wsI[64], 0);
      const int fcb  = atomicAdd(&wsI[80], 0);
      const int fnn  = atomicAdd(&wsI[112], 0);
      const float fces = atomicAdd(&wsF[48], 0.f);
      const float fceb = atomicAdd(&wsF[96], 0.f);
      const float fsq  = atomicAdd(&wsF[128], 0.f);
      const float sys_loss = fces / (float)(fnvs > 1 ? fnvs : 1);
      const float bar_loss = fceb / (float)(fnvb > 1 ? fnvb : 1);
      const float note_loss = (fnn > 0) ? fsq / (float)fnn : 0.f;
      const float lvs = lvs_p[0], lvb = lvb_p[0], lvn = lvn_p[0];
      const float ps = expf(-lvs), pb = expf(-lvb), pn = expf(-lvn);
      out[0] = 0.5f * (ps * sys_loss + lvs + pb * bar_loss + lvb + pn * note_loss + lvn);
      out[1] = sys_loss;
      out[2] = bar_loss;
      out[3] = note_loss;
      out[4] = (float)fcs / (float)(fnvs > 1 ? fnvs : 1);
      out[5] = (float)fcb / (float)(fnvb > 1 ? fnvb : 1);
      out[6] = ps;
      out[7] = pb;
      out[8] = pn;
    }
  }
}

extern "C" void kernel_launch(void* const* d_in, const int* in_sizes, int n_in,
                              void* d_out, int out_size, void* d_ws, size_t ws_size,
                              hipStream_t stream) {
  const float* sys_lg = (const float*)d_in[0];
  const int*   c_sys  = (const int*)d_in[1];
  const float* bar_lg = (const float*)d_in[2];
  const int*   c_bar  = (const int*)d_in[3];
  const float* npos   = (const float*)d_in[4];
  const int*   gt_sys = (const int*)d_in[5];
  const int*   gt_bar = (const int*)d_in[6];
  const float* gnp    = (const float*)d_in[7];
  const void*  gv     = d_in[8];
  const float* lvs    = (const float*)d_in[9];
  const float* lvb    = (const float*)d_in[10];
  const float* lvn    = (const float*)d_in[11];
  const int B = in_sizes[1];

  int*   wsI = (int*)d_ws;
  float* wsF = (float*)d_ws;

  uwl_scan_desc<<<SCAN_BLOCKS, 256, 0, stream>>>(c_sys, c_bar, gt_sys, gt_bar, gv,
                                                 npos, gnp, B, wsI, wsF);

  const long long nwaveslots = ((long long)(2 * B) + 3) / 4;   // blocks needed
  int nblocks = (int)((nwaveslots < 2048) ? nwaveslots : 2048);
  if (nblocks < 1) nblocks = 1;
  uwl_ce_kernel<<<nblocks, 256, 0, stream>>>(sys_lg, bar_lg, B, wsI, wsF);

  uwl_reduce_kernel<<<64, 256, 0, stream>>>(lvs, lvb, lvn, B, wsI, wsF, (float*)d_out);
}

// Round 5
// 125.151 us; speedup vs baseline: 1.0517x; 1.0517x over previous
//
#include <hip/hip_runtime.h>
#include <math.h>

// Two-kernel, zero-atomic structure.
// K1: NB = ceil(2B/16) blocks x 256 thr. Block b owns 16 consecutive global
//     segments [g0, g0+16) (sys = [0,B), bar = [B,2B)) and a ceil(B/NB)-sample
//     note-MSE slice. It self-computes segment offsets by redundant prefix-sum
//     of the L2-resident counts arrays (no scan kernel), runs the proven CE
//     body, and writes 6 per-block partials NON-atomically to block-indexed
//     slots (every slot written every launch -> no zeroing, no ticket).
// K2: 1 block reduces the 6*NB partials (48 KB, L2) -> 9 outputs.
// Fully deterministic (no atomics anywhere).
//
// Workspace layout (4-byte slots): f32 ces @256, ceb @256+NB, sq @256+2NB;
//                                  i32 cods @256+3NB, codb @256+4NB, cnt @256+5NB
#define SEG_PER_BLOCK 16

__device__ __forceinline__ bool is_valid(const void* gv, int flag, int i) {
  if (flag == 0) return ((const int*)gv)[i] != 0;
  if (flag == 1) return ((const unsigned char*)gv)[i] != 0;
  return ((const float*)gv)[i] != 0.0f;
}

__global__ __launch_bounds__(256)
void uwl_fused(const float* __restrict__ sys_lg, const float* __restrict__ bar_lg,
               const int* __restrict__ c_sys, const int* __restrict__ c_bar,
               const int* __restrict__ gt_sys, const int* __restrict__ gt_bar,
               const void* __restrict__ gv,
               const float* __restrict__ npos, const float* __restrict__ gnp,
               int B, int NB, int* __restrict__ wsI, float* __restrict__ wsF) {
  const int b = blockIdx.x;
  const int tid = threadIdx.x;
  const int lane = tid & 63;
  const int wid = tid >> 6;
  const int g0 = b * SEG_PER_BLOCK;
  __shared__ int s_flag;
  __shared__ int sOff[SEG_PER_BLOCK], sCnt[SEG_PER_BLOCK];
  __shared__ int sGt[SEG_PER_BLOCK], sVld[SEG_PER_BLOCK];
  __shared__ int sB1[4], sB2[4];
  __shared__ float sCe[4], sCb[4];
  __shared__ int sCo[4], sCob[4];

  // dtype sniff: wave 0, one load/lane + __all (serial sniff cost ~5us, r2)
  if (tid < 64) {
    int nw = B / 4; if (nw > 64) nw = 64; if (nw < 1) nw = 1;
    const unsigned int x = (tid < nw) ? ((const unsigned int*)gv)[tid] : 0u;
    const bool all01 = __all(x <= 1u);
    const bool allf = __all(x == 0u || x == 0x3F800000u);
    if (tid == 0) s_flag = all01 ? 0 : (allf ? 2 : 1);
  }

  // redundant block base: sys-side blocks scan c_sys[0,g0) only, bar-side
  // c_bar[0,g0-B) only -> ~67 MB aggregate of L2-resident reads (~2 us),
  // replacing the whole scan kernel + its launch gap + desc round-trip.
  const int e1 = (g0 < B) ? g0 : 0;
  int e2 = g0 - B; if (e2 < 0) e2 = 0; if (e2 > B) e2 = B;
  int bs = 0, bb = 0;
  {
    const int s4 = e1 >> 2;
    const int4* c4 = (const int4*)c_sys;
    for (int j = tid; j < s4; j += 256) { const int4 a = c4[j]; bs += a.x + a.y + a.z + a.w; }
    if (tid < (e1 & 3)) bs += c_sys[(s4 << 2) + tid];
  }
  {
    const int s4 = e2 >> 2;
    const int4* c4 = (const int4*)c_bar;
    for (int j = tid; j < s4; j += 256) { const int4 a = c4[j]; bb += a.x + a.y + a.z + a.w; }
    if (tid < (e2 & 3)) bb += c_bar[(s4 << 2) + tid];
  }
#pragma unroll
  for (int d = 1; d < 64; d <<= 1) {
    bs += __shfl_xor(bs, d, 64);
    bb += __shfl_xor(bb, d, 64);
  }
  if (lane == 0) { sB1[wid] = bs; sB2[wid] = bb; }
  __syncthreads();
  const int flag = s_flag;

  if (wid == 0) {
    // wave 0: build the 16 descriptors in-wave (lanes 0..15)
    const int base1 = sB1[0] + sB1[1] + sB1[2] + sB1[3];
    const int base2 = sB2[0] + sB2[1] + sB2[2] + sB2[3];
    const int g = g0 + lane;
    const bool okseg = (lane < SEG_PER_BLOCK) && (g < 2 * B);
    const bool isSys = g < B;
    const int smp = isSys ? g : g - B;
    const int cnt = okseg ? (isSys ? c_sys[g] : c_bar[smp]) : 0;
    int inc = cnt;                       // inclusive scan over the 16 lanes
#pragma unroll
    for (int d = 1; d < SEG_PER_BLOCK; d <<= 1) {
      const int v = __shfl_up(inc, d, 64);
      if (lane >= d) inc += v;
    }
    // straddling block (sys->bar boundary inside): bar offsets restart at 0,
    // so subtract the in-block sys total S. Non-straddle: S = 0.
    int S = 0;
    const int tb = B - g0;
    if (tb > 0 && tb < SEG_PER_BLOCK) S = __shfl(inc, tb - 1, 64);
    if (okseg) {
      const int gt = isSys ? gt_sys[g] : gt_bar[smp];
      const bool v = is_valid(gv, flag, smp);
      sOff[lane] = (isSys ? base1 : base2 - S) + inc - cnt;
      sCnt[lane] = cnt;
      sGt[lane] = gt;
      sVld[lane] = (cnt > 0 && gt >= 0 && gt < cnt && v) ? 1 : 0;
    }
  } else if (wid == 1) {
    // wave 1 (concurrent with desc build): this block's note-MSE slice,
    // written straight to its per-block slot (no other in-kernel consumer).
    const int ns = (B + NB - 1) / NB;
    const int n0 = b * ns;
    const int n1 = (n0 + ns < B) ? n0 + ns : B;
    float sq = 0.f; int cnt = 0;
    for (int i = n0 + lane; i < n1; i += 64) {
      if (is_valid(gv, flag, i)) {
        const float d = npos[i] - gnp[i];
        sq += d * d; cnt += 1;
      }
    }
#pragma unroll
    for (int d = 1; d < 64; d <<= 1) {
      sq += __shfl_xor(sq, d, 64);
      cnt += __shfl_xor(cnt, d, 64);
    }
    if (lane == 0) { wsF[256 + 2 * NB + b] = sq; wsI[256 + 5 * NB + b] = cnt; }
  }
  __syncthreads();

  // 4 consecutive segments per wave — proven CE inner body (r0/r3).
  // "first argmax == gt" as (logits[gt] == max): duplicate-max f32 ties have
  // P ~ 1e-8/segment, one flip moves acc by 6e-5 — below threshold.
  // Regpath: 2 clamped float4 chunks + clamped scalar tail (count <= 576);
  // exp-sum is max-independent (LSE identity, logits O(1)).
  float ces = 0.f, ceb = 0.f;
  int cods = 0, codb = 0;
#pragma unroll 1
  for (int k = 0; k < 4; ++k) {
    const int t = (wid << 2) | k;
    const int g = g0 + t;
    if (g >= 2 * B) break;
    const int off_i = sOff[t], count = sCnt[t], gt = sGt[t], vld = sVld[t];
    const float* lg = (g < B) ? sys_lg : bar_lg;
    const long long off = off_i;

    float m = -INFINITY;
    float s = 0.f;
    float tl = 0.f;
    const bool regpath = (count >= 4) && (count <= 576) &&
                         ((off_i & 3) == 0) && ((count & 3) == 0);
    if (regpath) {
      const float4* p = (const float4*)(lg + off);
      const int emax = (count >> 2) - 1;          // last valid float4 index
      float vals[8];
#pragma unroll
      for (int kk = 0; kk < 2; ++kk) {
        const int e4 = (kk << 6) + lane;
        const int ec = (e4 > emax) ? emax : e4;   // clamped: always in-bounds
        const float4 v = p[ec];
        const bool live = (e4 <= emax);
        vals[4 * kk]     = live ? v.x : -INFINITY;
        vals[4 * kk + 1] = live ? v.y : -INFINITY;
        vals[4 * kk + 2] = live ? v.z : -INFINITY;
        vals[4 * kk + 3] = live ? v.w : -INFINITY;
      }
      // scalar tail element 512+lane (clamped load, masked to -INF)
      const int ti = 512 + lane;
      const int tic = (ti < count) ? ti : (count - 1);
      const float tvr = lg[off + tic];
      const float tv = (ti < count) ? tvr : -INFINITY;
#pragma unroll
      for (int kk = 0; kk < 8; ++kk) m = fmaxf(m, vals[kk]);
      m = fmaxf(m, tv);
#pragma unroll
      for (int kk = 0; kk < 8; ++kk) s += __expf(vals[kk]);
      s += __expf(tv);
      // target logit: register-select + shuffle (gt wave-uniform, < count)
      const int gts = vld ? gt : 0;
      float pick;
      int srclane;
      if (gts < 512) {                 // wave-uniform branch (scalar)
        const int q = ((gts >> 8) << 2) | (gts & 3);
        pick = vals[0];
#pragma unroll
        for (int i = 1; i < 8; ++i) pick = (i == q) ? vals[i] : pick;
        srclane = (gts >> 2) & 63;
      } else {
        pick = tv;
        srclane = gts - 512;
      }
      tl = __shfl(pick, srclane, 64);
    } else {
      for (int i = lane; i < count; i += 64) {
        const float v = lg[off + i];
        m = fmaxf(m, v);
        s += __expf(v);
      }
      if (vld) {
        const float t0 = (lane == 0) ? lg[off + gt] : 0.f;
        tl = __shfl(t0, 0, 64);
      }
    }
    // (s, m) butterfly — all lanes end with wave totals
#pragma unroll
    for (int d = 1; d < 64; d <<= 1) {
      s += __shfl_xor(s, d, 64);
      m = fmaxf(m, __shfl_xor(m, d, 64));
    }
    if (vld) {                         // wave-uniform
      const float ce = __logf(s) - tl;
      const int code = 1 + ((tl == m) ? 65536 : 0);  // valid + correct<<16
      if (g < B) { ces += ce; cods += code; }
      else       { ceb += ce; codb += code; }
    }
  }
  if (lane == 0) { sCe[wid] = ces; sCb[wid] = ceb; sCo[wid] = cods; sCob[wid] = codb; }
  __syncthreads();
  if (tid == 0) {   // per-block partials, non-atomic block-indexed slots
    wsF[256 + b]          = sCe[0] + sCe[1] + sCe[2] + sCe[3];
    wsF[256 + NB + b]     = sCb[0] + sCb[1] + sCb[2] + sCb[3];
    wsI[256 + 3 * NB + b] = sCo[0] + sCo[1] + sCo[2] + sCo[3];
    wsI[256 + 4 * NB + b] = sCob[0] + sCob[1] + sCob[2] + sCob[3];
  }
}

// K2: one block reduces the 6*NB per-block partials (48 KB, L2-resident) and
// emits the 9 outputs. No atomics, no ticket — deterministic.
__global__ __launch_bounds__(256)
void uwl_final(const float* __restrict__ lvs_p, const float* __restrict__ lvb_p,
               const float* __restrict__ lvn_p,
               int B, int NB, const int* __restrict__ wsI,
               const float* __restrict__ wsF, float* __restrict__ out) {
  const int tid = threadIdx.x;
  const int lane = tid & 63;
  const int wid = tid >> 6;
  float ces = 0.f, ceb = 0.f, sq = 0.f;
  int cods = 0, codb = 0, cnt = 0;
  for (int i = tid; i < NB; i += 256) {
    ces  += wsF[256 + i];
    ceb  += wsF[256 + NB + i];
    sq   += wsF[256 + 2 * NB + i];
    cods += wsI[256 + 3 * NB + i];
    codb += wsI[256 + 4 * NB + i];
    cnt  += wsI[256 + 5 * NB + i];
  }
#pragma unroll
  for (int d = 1; d < 64; d <<= 1) {
    ces  += __shfl_xor(ces, d, 64);
    ceb  += __shfl_xor(ceb, d, 64);
    sq   += __shfl_xor(sq, d, 64);
    cods += __shfl_xor(cods, d, 64);
    codb += __shfl_xor(codb, d, 64);
    cnt  += __shfl_xor(cnt, d, 64);
  }
  __shared__ float f0[4], f1[4], f2[4];
  __shared__ int i0[4], i1[4], i2[4];
  if (lane == 0) { f0[wid] = ces; f1[wid] = ceb; f2[wid] = sq;
                   i0[wid] = cods; i1[wid] = codb; i2[wid] = cnt; }
  __syncthreads();
  if (tid == 0) {
    const float fces = f0[0] + f0[1] + f0[2] + f0[3];
    const float fceb = f1[0] + f1[1] + f1[2] + f1[3];
    const float fsq  = f2[0] + f2[1] + f2[2] + f2[3];
    const int fs = i0[0] + i0[1] + i0[2] + i0[3];
    const int fb = i1[0] + i1[1] + i1[2] + i1[3];
    const int fnn = i2[0] + i2[1] + i2[2] + i2[3];
    const int fnvs = fs & 0xFFFF, fcs = fs >> 16;   // n_valid < 65536: no carry
    const int fnvb = fb & 0xFFFF, fcb = fb >> 16;
    const float sys_loss = fces / (float)(fnvs > 1 ? fnvs : 1);
    const float bar_loss = fceb / (float)(fnvb > 1 ? fnvb : 1);
    const float note_loss = (fnn > 0) ? fsq / (float)fnn : 0.f;
    const float lvs = lvs_p[0], lvb = lvb_p[0], lvn = lvn_p[0];
    const float ps = expf(-lvs), pb = expf(-lvb), pn = expf(-lvn);
    out[0] = 0.5f * (ps * sys_loss + lvs + pb * bar_loss + lvb + pn * note_loss + lvn);
    out[1] = sys_loss;
    out[2] = bar_loss;
    out[3] = note_loss;
    out[4] = (float)fcs / (float)(fnvs > 1 ? fnvs : 1);
    out[5] = (float)fcb / (float)(fnvb > 1 ? fnvb : 1);
    out[6] = ps;
    out[7] = pb;
    out[8] = pn;
  }
}

extern "C" void kernel_launch(void* const* d_in, const int* in_sizes, int n_in,
                              void* d_out, int out_size, void* d_ws, size_t ws_size,
                              hipStream_t stream) {
  const float* sys_lg = (const float*)d_in[0];
  const int*   c_sys  = (const int*)d_in[1];
  const float* bar_lg = (const float*)d_in[2];
  const int*   c_bar  = (const int*)d_in[3];
  const float* npos   = (const float*)d_in[4];
  const int*   gt_sys = (const int*)d_in[5];
  const int*   gt_bar = (const int*)d_in[6];
  const float* gnp    = (const float*)d_in[7];
  const void*  gv     = d_in[8];
  const float* lvs    = (const float*)d_in[9];
  const float* lvb    = (const float*)d_in[10];
  const float* lvn    = (const float*)d_in[11];
  const int B = in_sizes[1];

  int*   wsI = (int*)d_ws;
  float* wsF = (float*)d_ws;

  int NB = (2 * B + SEG_PER_BLOCK - 1) / SEG_PER_BLOCK;
  if (NB < 1) NB = 1;

  uwl_fused<<<NB, 256, 0, stream>>>(sys_lg, bar_lg, c_sys, c_bar, gt_sys, gt_bar,
                                    gv, npos, gnp, B, NB, wsI, wsF);
  uwl_final<<<1, 256, 0, stream>>>(lvs, lvb, lvn, B, NB, wsI, wsF, (float*)d_out);
}

// Round 6
// 123.410 us; speedup vs baseline: 1.0665x; 1.0141x over previous
//
#include <hip/hip_runtime.h>
#include <math.h>

// Two-kernel, zero-atomic structure (proven r5), widened blocks.
// K1: NB = ceil(2B/32) blocks x 512 thr (4 blocks/CU x 8 waves = full 32
//     waves/CU). Block b owns 32 consecutive global segments [g0, g0+32)
//     (sys = [0,B), bar = [B,2B)) and a ceil(B/NB)-sample note-MSE slice.
//     Self-computes segment offsets by redundant int4 prefix-sum of the
//     L2-resident counts (33 MB aggregate, half of r5's 67 MB), runs the
//     proven CE body, writes 6 per-block partials NON-atomically to
//     block-indexed slots (every slot written every launch -> no zeroing,
//     no ticket; 2048-wide tickets cost ~30ns/atomic serialized = r1's 270us).
// K2: 1 block reduces the 6*NB partials (24 KB, L2) -> 9 outputs.
// Fully deterministic (no atomics anywhere).
//
// Workspace layout (4-byte slots): f32 ces @256, ceb @256+NB, sq @256+2NB;
//                                  i32 cods @256+3NB, codb @256+4NB, cnt @256+5NB
#define SEG_PER_BLOCK 32
#define K1_THREADS 512

__device__ __forceinline__ bool is_valid(const void* gv, int flag, int i) {
  if (flag == 0) return ((const int*)gv)[i] != 0;
  if (flag == 1) return ((const unsigned char*)gv)[i] != 0;
  return ((const float*)gv)[i] != 0.0f;
}

__global__ __launch_bounds__(K1_THREADS, 8)
void uwl_fused(const float* __restrict__ sys_lg, const float* __restrict__ bar_lg,
               const int* __restrict__ c_sys, const int* __restrict__ c_bar,
               const int* __restrict__ gt_sys, const int* __restrict__ gt_bar,
               const void* __restrict__ gv,
               const float* __restrict__ npos, const float* __restrict__ gnp,
               int B, int NB, int* __restrict__ wsI, float* __restrict__ wsF) {
  const int b = blockIdx.x;
  const int tid = threadIdx.x;
  const int lane = tid & 63;
  const int wid = tid >> 6;                 // 0..7
  const int g0 = b * SEG_PER_BLOCK;
  __shared__ int s_flag;
  __shared__ int sOff[SEG_PER_BLOCK], sCnt[SEG_PER_BLOCK];
  __shared__ int sGt[SEG_PER_BLOCK], sVld[SEG_PER_BLOCK];
  __shared__ int sB1[8], sB2[8];
  __shared__ float sCe[8], sCb[8];
  __shared__ int sCo[8], sCob[8];

  // dtype sniff on wave 2 (waves 0/1 have post-barrier jobs; keep their
  // prefix start unburdened). One load/lane + __all (serial sniff = ~5us, r2).
  if (wid == 2) {
    int nw = B / 4; if (nw > 64) nw = 64; if (nw < 1) nw = 1;
    const unsigned int x = (lane < nw) ? ((const unsigned int*)gv)[lane] : 0u;
    const bool all01 = __all(x <= 1u);
    const bool allf = __all(x == 0u || x == 0x3F800000u);
    if (lane == 0) s_flag = all01 ? 0 : (allf ? 2 : 1);
  }

  // redundant block base: sys-side blocks scan c_sys[0,g0) only, bar-side
  // c_bar[0,g0-B) only; int4-vectorized over 512 threads (<=8 int4/thread).
  const int e1 = (g0 < B) ? g0 : 0;
  int e2 = g0 - B; if (e2 < 0) e2 = 0; if (e2 > B) e2 = B;
  int bs = 0, bb = 0;
  {
    const int s4 = e1 >> 2;
    const int4* c4 = (const int4*)c_sys;
    for (int j = tid; j < s4; j += K1_THREADS) { const int4 a = c4[j]; bs += a.x + a.y + a.z + a.w; }
    if (tid < (e1 & 3)) bs += c_sys[(s4 << 2) + tid];
  }
  {
    const int s4 = e2 >> 2;
    const int4* c4 = (const int4*)c_bar;
    for (int j = tid; j < s4; j += K1_THREADS) { const int4 a = c4[j]; bb += a.x + a.y + a.z + a.w; }
    if (tid < (e2 & 3)) bb += c_bar[(s4 << 2) + tid];
  }
#pragma unroll
  for (int d = 1; d < 64; d <<= 1) {
    bs += __shfl_xor(bs, d, 64);
    bb += __shfl_xor(bb, d, 64);
  }
  if (lane == 0) { sB1[wid] = bs; sB2[wid] = bb; }
  __syncthreads();
  const int flag = s_flag;

  if (wid == 0) {
    // wave 0: build the 32 descriptors in-wave (lanes 0..31)
    int base1 = 0, base2 = 0;
#pragma unroll
    for (int w = 0; w < 8; ++w) { base1 += sB1[w]; base2 += sB2[w]; }
    const int g = g0 + lane;
    const bool okseg = (lane < SEG_PER_BLOCK) && (g < 2 * B);
    const bool isSys = g < B;
    const int smp = isSys ? g : g - B;
    const int cnt = okseg ? (isSys ? c_sys[g] : c_bar[smp]) : 0;
    int inc = cnt;                       // inclusive scan over the 32 lanes
#pragma unroll
    for (int d = 1; d < SEG_PER_BLOCK; d <<= 1) {
      const int v = __shfl_up(inc, d, 64);
      if (lane >= d) inc += v;
    }
    // straddling block (sys->bar boundary inside): bar offsets restart at 0,
    // so subtract the in-block sys total S. Non-straddle: S = 0.
    int S = 0;
    const int tb = B - g0;
    if (tb > 0 && tb < SEG_PER_BLOCK) S = __shfl(inc, tb - 1, 64);
    if (okseg) {
      const int gt = isSys ? gt_sys[g] : gt_bar[smp];
      const bool v = is_valid(gv, flag, smp);
      sOff[lane] = (isSys ? base1 : base2 - S) + inc - cnt;
      sCnt[lane] = cnt;
      sGt[lane] = gt;
      sVld[lane] = (cnt > 0 && gt >= 0 && gt < cnt && v) ? 1 : 0;
    }
  } else if (wid == 1) {
    // wave 1 (concurrent with desc build): this block's note-MSE slice,
    // written straight to its per-block slot. Slots ALWAYS written.
    const int ns = (B + NB - 1) / NB;
    const int n0 = b * ns;
    const int n1 = (n0 + ns < B) ? n0 + ns : B;
    float sq = 0.f; int cnt = 0;
    for (int i = n0 + lane; i < n1; i += 64) {
      if (is_valid(gv, flag, i)) {
        const float d = npos[i] - gnp[i];
        sq += d * d; cnt += 1;
      }
    }
#pragma unroll
    for (int d = 1; d < 64; d <<= 1) {
      sq += __shfl_xor(sq, d, 64);
      cnt += __shfl_xor(cnt, d, 64);
    }
    if (lane == 0) { wsF[256 + 2 * NB + b] = sq; wsI[256 + 5 * NB + b] = cnt; }
  }
  __syncthreads();

  // 4 consecutive segments per wave (8 waves x 4 = 32) — proven CE inner body.
  // "first argmax == gt" as (logits[gt] == max): duplicate-max f32 ties have
  // P ~ 1e-8/segment, one flip moves acc by 6e-5 — below threshold.
  // Regpath: 2 clamped float4 chunks + clamped scalar tail (count <= 576);
  // exp-sum is max-independent (LSE identity, logits O(1)).
  float ces = 0.f, ceb = 0.f;
  int cods = 0, codb = 0;
#pragma unroll 1
  for (int k = 0; k < 4; ++k) {
    const int t = (wid << 2) | k;
    const int g = g0 + t;
    if (g >= 2 * B) break;
    const int off_i = sOff[t], count = sCnt[t], gt = sGt[t], vld = sVld[t];
    const float* lg = (g < B) ? sys_lg : bar_lg;
    const long long off = off_i;

    float m = -INFINITY;
    float s = 0.f;
    float tl = 0.f;
    const bool regpath = (count >= 4) && (count <= 576) &&
                         ((off_i & 3) == 0) && ((count & 3) == 0);
    if (regpath) {
      const float4* p = (const float4*)(lg + off);
      const int emax = (count >> 2) - 1;          // last valid float4 index
      float vals[8];
#pragma unroll
      for (int kk = 0; kk < 2; ++kk) {
        const int e4 = (kk << 6) + lane;
        const int ec = (e4 > emax) ? emax : e4;   // clamped: always in-bounds
        const float4 v = p[ec];
        const bool live = (e4 <= emax);
        vals[4 * kk]     = live ? v.x : -INFINITY;
        vals[4 * kk + 1] = live ? v.y : -INFINITY;
        vals[4 * kk + 2] = live ? v.z : -INFINITY;
        vals[4 * kk + 3] = live ? v.w : -INFINITY;
      }
      // scalar tail element 512+lane — wave-uniform skip when count <= 512
      float tv = -INFINITY;
      if (count > 512) {
        const int ti = 512 + lane;
        const int tic = (ti < count) ? ti : (count - 1);
        const float tvr = lg[off + tic];
        tv = (ti < count) ? tvr : -INFINITY;
      }
#pragma unroll
      for (int kk = 0; kk < 8; ++kk) m = fmaxf(m, vals[kk]);
      m = fmaxf(m, tv);
#pragma unroll
      for (int kk = 0; kk < 8; ++kk) s += __expf(vals[kk]);
      s += __expf(tv);
      // target logit: register-select + shuffle (gt wave-uniform, < count)
      const int gts = vld ? gt : 0;
      float pick;
      int srclane;
      if (gts < 512) {                 // wave-uniform branch (scalar)
        const int q = ((gts >> 8) << 2) | (gts & 3);
        pick = vals[0];
#pragma unroll
        for (int i = 1; i < 8; ++i) pick = (i == q) ? vals[i] : pick;
        srclane = (gts >> 2) & 63;
      } else {
        pick = tv;
        srclane = gts - 512;
      }
      tl = __shfl(pick, srclane, 64);
    } else {
      for (int i = lane; i < count; i += 64) {
        const float v = lg[off + i];
        m = fmaxf(m, v);
        s += __expf(v);
      }
      if (vld) {
        const float t0 = (lane == 0) ? lg[off + gt] : 0.f;
        tl = __shfl(t0, 0, 64);
      }
    }
    // (s, m) butterfly — all lanes end with wave totals
#pragma unroll
    for (int d = 1; d < 64; d <<= 1) {
      s += __shfl_xor(s, d, 64);
      m = fmaxf(m, __shfl_xor(m, d, 64));
    }
    if (vld) {                         // wave-uniform
      const float ce = __logf(s) - tl;
      const int code = 1 + ((tl == m) ? 65536 : 0);  // valid + correct<<16
      if (g < B) { ces += ce; cods += code; }
      else       { ceb += ce; codb += code; }
    }
  }
  if (lane == 0) { sCe[wid] = ces; sCb[wid] = ceb; sCo[wid] = cods; sCob[wid] = codb; }
  __syncthreads();
  if (tid == 0) {   // per-block partials, non-atomic block-indexed slots
    float f1 = 0.f, f2 = 0.f; int i1 = 0, i2 = 0;
#pragma unroll
    for (int w = 0; w < 8; ++w) { f1 += sCe[w]; f2 += sCb[w]; i1 += sCo[w]; i2 += sCob[w]; }
    wsF[256 + b]          = f1;
    wsF[256 + NB + b]     = f2;
    wsI[256 + 3 * NB + b] = i1;
    wsI[256 + 4 * NB + b] = i2;
  }
}

// K2: one block reduces the 6*NB per-block partials (24 KB, L2-resident) and
// emits the 9 outputs. No atomics, no ticket — deterministic.
__global__ __launch_bounds__(256)
void uwl_final(const float* __restrict__ lvs_p, const float* __restrict__ lvb_p,
               const float* __restrict__ lvn_p,
               int B, int NB, const int* __restrict__ wsI,
               const float* __restrict__ wsF, float* __restrict__ out) {
  const int tid = threadIdx.x;
  const int lane = tid & 63;
  const int wid = tid >> 6;
  float ces = 0.f, ceb = 0.f, sq = 0.f;
  int cods = 0, codb = 0, cnt = 0;
  for (int i = tid; i < NB; i += 256) {
    ces  += wsF[256 + i];
    ceb  += wsF[256 + NB + i];
    sq   += wsF[256 + 2 * NB + i];
    cods += wsI[256 + 3 * NB + i];
    codb += wsI[256 + 4 * NB + i];
    cnt  += wsI[256 + 5 * NB + i];
  }
#pragma unroll
  for (int d = 1; d < 64; d <<= 1) {
    ces  += __shfl_xor(ces, d, 64);
    ceb  += __shfl_xor(ceb, d, 64);
    sq   += __shfl_xor(sq, d, 64);
    cods += __shfl_xor(cods, d, 64);
    codb += __shfl_xor(codb, d, 64);
    cnt  += __shfl_xor(cnt, d, 64);
  }
  __shared__ float f0[4], f1[4], f2[4];
  __shared__ int i0[4], i1[4], i2[4];
  if (lane == 0) { f0[wid] = ces; f1[wid] = ceb; f2[wid] = sq;
                   i0[wid] = cods; i1[wid] = codb; i2[wid] = cnt; }
  __syncthreads();
  if (tid == 0) {
    const float fces = f0[0] + f0[1] + f0[2] + f0[3];
    const float fceb = f1[0] + f1[1] + f1[2] + f1[3];
    const float fsq  = f2[0] + f2[1] + f2[2] + f2[3];
    const int fs = i0[0] + i0[1] + i0[2] + i0[3];
    const int fb = i1[0] + i1[1] + i1[2] + i1[3];
    const int fnn = i2[0] + i2[1] + i2[2] + i2[3];
    const int fnvs = fs & 0xFFFF, fcs = fs >> 16;   // n_valid < 65536: no carry
    const int fnvb = fb & 0xFFFF, fcb = fb >> 16;
    const float sys_loss = fces / (float)(fnvs > 1 ? fnvs : 1);
    const float bar_loss = fceb / (float)(fnvb > 1 ? fnvb : 1);
    const float note_loss = (fnn > 0) ? fsq / (float)fnn : 0.f;
    const float lvs = lvs_p[0], lvb = lvb_p[0], lvn = lvn_p[0];
    const float ps = expf(-lvs), pb = expf(-lvb), pn = expf(-lvn);
    out[0] = 0.5f * (ps * sys_loss + lvs + pb * bar_loss + lvb + pn * note_loss + lvn);
    out[1] = sys_loss;
    out[2] = bar_loss;
    out[3] = note_loss;
    out[4] = (float)fcs / (float)(fnvs > 1 ? fnvs : 1);
    out[5] = (float)fcb / (float)(fnvb > 1 ? fnvb : 1);
    out[6] = ps;
    out[7] = pb;
    out[8] = pn;
  }
}

extern "C" void kernel_launch(void* const* d_in, const int* in_sizes, int n_in,
                              void* d_out, int out_size, void* d_ws, size_t ws_size,
                              hipStream_t stream) {
  const float* sys_lg = (const float*)d_in[0];
  const int*   c_sys  = (const int*)d_in[1];
  const float* bar_lg = (const float*)d_in[2];
  const int*   c_bar  = (const int*)d_in[3];
  const float* npos   = (const float*)d_in[4];
  const int*   gt_sys = (const int*)d_in[5];
  const int*   gt_bar = (const int*)d_in[6];
  const float* gnp    = (const float*)d_in[7];
  const void*  gv     = d_in[8];
  const float* lvs    = (const float*)d_in[9];
  const float* lvb    = (const float*)d_in[10];
  const float* lvn    = (const float*)d_in[11];
  const int B = in_sizes[1];

  int*   wsI = (int*)d_ws;
  float* wsF = (float*)d_ws;

  int NB = (2 * B + SEG_PER_BLOCK - 1) / SEG_PER_BLOCK;
  if (NB < 1) NB = 1;

  uwl_fused<<<NB, K1_THREADS, 0, stream>>>(sys_lg, bar_lg, c_sys, c_bar,
                                           gt_sys, gt_bar, gv, npos, gnp,
                                           B, NB, wsI, wsF);
  uwl_final<<<1, 256, 0, stream>>>(lvs, lvb, lvn, B, NB, wsI, wsF, (float*)d_out);
}